// Round 2
// baseline (208.808 us; speedup 1.0000x reference)
//
#include <hip/hip_runtime.h>
#include <stdint.h>

#define K_DIM 8192
#define N_DIM 28672
#define NG    16   // scale-groups per wave (K/4 waves / 128-group)

typedef _Float16 half8 __attribute__((ext_vector_type(8)));
typedef _Float16 half2t __attribute__((ext_vector_type(2)));
typedef float f32x16 __attribute__((ext_vector_type(16)));

// ---- prep: x f32 [32][8192] -> xp f16 [K/8][32][8] in A-fragment slot order
__global__ __launch_bounds__(256) void prep_x(const float* __restrict__ x,
                                              _Float16* __restrict__ xp) {
  int idx = blockIdx.x * 256 + threadIdx.x;  // 32768 = 1024 word-rows * 32 m
  int m  = idx & 31;
  int k8 = idx >> 5;
  const float* p = x + (size_t)m * K_DIM + (size_t)k8 * 8;
  float4 xa = *(const float4*)p;
  float4 xb = *(const float4*)(p + 4);
  half2t p0 = __builtin_bit_cast(half2t, __builtin_amdgcn_cvt_pkrtz(xa.x, xb.x));
  half2t p1 = __builtin_bit_cast(half2t, __builtin_amdgcn_cvt_pkrtz(xa.y, xb.y));
  half2t p2 = __builtin_bit_cast(half2t, __builtin_amdgcn_cvt_pkrtz(xa.z, xb.z));
  half2t p3 = __builtin_bit_cast(half2t, __builtin_amdgcn_cvt_pkrtz(xa.w, xb.w));
  half8 o;
  o[0] = p0[0]; o[1] = p0[1]; o[2] = p1[0]; o[3] = p1[1];
  o[4] = p2[0]; o[5] = p2[1]; o[6] = p3[0]; o[7] = p3[1];
  *(half8*)(xp + ((size_t)k8 * 32 + m) * 8) = o;
}

// int4 word -> 8 f16 slots [n0,n4,n1,n5,n2,n6,n3,n7], value (n-8)*s (exact add)
static __device__ __forceinline__ half8 dqs(uint32_t w, half2t sh) {
  const uint32_t M4 = 0x000F000Fu, E = 0x64006400u;
  half2t off; off[0] = (_Float16)(-1032.0f); off[1] = (_Float16)(-1032.0f);
  half2t v0 = (__builtin_bit_cast(half2t, ( w        & M4) | E) + off) * sh;
  half2t v1 = (__builtin_bit_cast(half2t, ((w >> 4)  & M4) | E) + off) * sh;
  half2t v2 = (__builtin_bit_cast(half2t, ((w >> 8)  & M4) | E) + off) * sh;
  half2t v3 = (__builtin_bit_cast(half2t, ((w >> 12) & M4) | E) + off) * sh;
  half8 r;
  r[0] = v0[0]; r[1] = v0[1]; r[2] = v1[0]; r[3] = v1[1];
  r[4] = v2[0]; r[5] = v2[1]; r[6] = v3[0]; r[7] = v3[1];
  return r;
}

// gfx9 s_waitcnt imm: vm[3:0]|[15:14], exp[6:4]=7 (none), lgkm[11:8]=15 (none)
static __device__ __forceinline__ void waitcnt_vm8() { __builtin_amdgcn_s_waitcnt(0x0F78); }
static __device__ __forceinline__ void waitcnt_vm0() { __builtin_amdgcn_s_waitcnt(0x0F70); }

// One block per 32-col tile (896 blocks, all resident). 4 waves split K:
// wave w owns word-rows [w*256, w*256+256) = 16 scale-groups. No split-K
// atomics, no LDS staging (xp is 512KB, L2-hot -> direct VGPR loads), no
// barriers in the K-loop. All loop VMEM is pinned asm in fixed order:
// steady queue = [Q(g),S(g),A(g),Q(g+1)] -> wait vmcnt(8) per group
// (Q 2-group lead covers HBM ~900cy; A/S 1-group lead covers L2 ~300cy).
// Single LDS reduction + one store of out at the end.
__global__ __launch_bounds__(256, 4) void qgemm(
    const uint32_t* __restrict__ q, const float* __restrict__ scales,
    const float* __restrict__ bias, const _Float16* __restrict__ xp,
    float* __restrict__ out) {
  __shared__ float red[4][16][64];   // 16 KB cross-wave reduce buffer
  const int tid  = threadIdx.x;
  const int w    = tid >> 6;
  const int lane = tid & 63;
  const int h    = lane >> 5;
  const int nl   = lane & 31;
  const int ct   = blockIdx.x;       // 32-col tile
  const int c0   = ct << 5;
  const int wr0  = w << 8;           // wave's first word-row

  // 32-bit voffsets (max ~117MB < 4GB)
  const uint32_t qb  = (uint32_t)((((uint64_t)(wr0 + h)) * N_DIM + c0 + nl) * 4);
  const uint32_t ab  = (uint32_t)(((wr0 + h) * 32 + nl) * 16);
  const uint32_t sb  = (uint32_t)((((uint64_t)(w * NG)) * N_DIM + c0 + nl) * 4);

  uint32_t qr[2][8];   // Q words, double-buffered
  float4   aA[2][8];   // A fragments (half8 bits), double-buffered
  uint32_t sv[2];      // group scale (f32 bits)

  auto qload = [&](int g, int p) {
#pragma unroll
    for (int i = 0; i < 8; i++) {
      uint32_t vo = qb + (uint32_t)(g * 16 + 2 * i) * (uint32_t)(N_DIM * 4);
      asm volatile("global_load_dword %0, %1, %2"
                   : "=v"(qr[p][i]) : "v"(vo), "s"(q));
    }
  };
  auto aload = [&](int g, int p) {
#pragma unroll
    for (int i = 0; i < 8; i++) {
      uint32_t vo = ab + (uint32_t)(g * 8192 + i * 1024);
      asm volatile("global_load_dwordx4 %0, %1, %2"
                   : "=v"(aA[p][i]) : "v"(vo), "s"(xp));
    }
  };
  auto sload = [&](int g, int p) {
    uint32_t vo = sb + (uint32_t)g * (uint32_t)(N_DIM * 4);
    asm volatile("global_load_dword %0, %1, %2"
                 : "=v"(sv[p]) : "v"(vo), "s"(scales));
  };

  f32x16 acc;
#pragma unroll
  for (int j = 0; j < 16; j++) acc[j] = 0.0f;

  // prologue queue: [Q0(8), S0, A0(8), Q1(8)]
  qload(0, 0); sload(0, 0); aload(0, 0); qload(1, 1);

  auto step = [&](int g, int p) {
    if (g == NG - 1) waitcnt_vm0(); else waitcnt_vm8();
    __builtin_amdgcn_sched_barrier(0);   // rule #18: no consumer hoists above
    float sf = __builtin_bit_cast(float, sv[p]);
    half2t s2 = __builtin_bit_cast(half2t, __builtin_amdgcn_cvt_pkrtz(sf, sf));
#pragma unroll
    for (int i = 0; i < 8; i++) {
      acc = __builtin_amdgcn_mfma_f32_32x32x16_f16(
          __builtin_bit_cast(half8, aA[p][i]), dqs(qr[p][i], s2), acc, 0, 0, 0);
    }
    // prefetch after consumption (WAR on same buffers is program-ordered)
    if (g + 1 < NG) { sload(g + 1, p ^ 1); aload(g + 1, p ^ 1); }
    if (g + 2 < NG) qload(g + 2, p);
  };

#pragma unroll 2
  for (int gg = 0; gg < NG; gg += 2) {
    step(gg, 0);
    step(gg + 1, 1);
  }

  // cross-wave K reduction: red[w][j][lane], conflict-free stride-1
#pragma unroll
  for (int j = 0; j < 16; j++) red[w][j][lane] = acc[j];
  __syncthreads();

  float b = bias[c0 + nl];
#pragma unroll
  for (int jj = 0; jj < 4; jj++) {
    int j = w * 4 + jj;
    float v = red[0][j][lane] + red[1][j][lane] +
              red[2][j][lane] + red[3][j][lane];
    int row = (j & 3) + ((j >> 2) << 3) + (h << 2);
    out[(size_t)row * N_DIM + c0 + nl] = v + b;
  }
}

extern "C" void kernel_launch(void* const* d_in, const int* in_sizes, int n_in,
                              void* d_out, int out_size, void* d_ws, size_t ws_size,
                              hipStream_t stream) {
  const float*    xf      = (const float*)d_in[0];
  const uint32_t* qweight = (const uint32_t*)d_in[1];
  const float*    scales  = (const float*)d_in[2];
  const float*    bias    = (const float*)d_in[3];
  float*          out     = (float*)d_out;
  _Float16*       xp      = (_Float16*)d_ws;   // 512 KB scratch

  prep_x<<<dim3(128), dim3(256), 0, stream>>>(xf, xp);
  qgemm<<<dim3(N_DIM / 32), dim3(256), 0, stream>>>(qweight, scales, bias, xp, out);
}